// Round 1
// baseline (1344.045 us; speedup 1.0000x reference)
//
#include <hip/hip_runtime.h>

// QLSTM: T=512 steps, B=256 batch, IN=128, HID=256, NQ=32, D=IN+HID=384.
// z[b,g,n]  = sum_d comb[b,d]*W_gates[g,n,d] + b_gates[g,n]      (gn = g*32+n, 128 cols)
// h4[b,g,h] = sum_n z[b,g,n]*Wh[h,n] + bh[h]
// f,i = sigmoid(h4[0,1]); g = tanh(h4[2]); o = sigmoid(h4[3])
// c' = f*c + i*g ; h' = o*tanh(c')
// Output: outputs (T,B,HID) ++ hx (B,HID) ++ cx (B,HID), all fp32.
//
// Design: one workgroup per batch row (256 blocks x 256 threads), the whole
// T-loop runs inside the block with __syncthreads() only (no grid sync).
// Gate weights live entirely in VGPRs: thread t=(gn=t>>1, kh=t&1) holds
// wx[64] (x-part of comb) + wk[128] (h-part) of W_gates row gn, plus the
// Wh row for h-unit t (wh[32]). h / x-row / z go through LDS as wave-uniform
// broadcasts. c and h for unit t stay in registers.

#define T_STEPS 512
#define BATCH   256
#define INDIM   128
#define HIDDEN  256
#define GNCOLS  128

__device__ __forceinline__ float sigmoid_f(float x) {
    return 1.0f / (1.0f + __expf(-x));
}
__device__ __forceinline__ float tanh_f(float x) {
    float e = __expf(2.0f * x);
    return (e - 1.0f) / (e + 1.0f);
}

__global__ __launch_bounds__(256, 1) void qlstm_kernel(
    const float* __restrict__ x,    // (T,B,IN)
    const float* __restrict__ Wg,   // (4,32,384) row-major
    const float* __restrict__ bg,   // (4,32)
    const float* __restrict__ Wh,   // (256,32)
    const float* __restrict__ bh,   // (256)
    float* __restrict__ out)        // T*B*HID ++ B*HID ++ B*HID
{
    __shared__ float h_lds[HIDDEN];
    __shared__ float x_lds[INDIM];
    __shared__ float z_lds[GNCOLS];

    const int tid = threadIdx.x;
    const int b   = blockIdx.x;
    const int gn  = tid >> 1;   // 0..127 : gate-col (g*32+n)
    const int kh  = tid & 1;    // k-half within the K reduction

    // ---- load per-thread weight registers (one-time) ----
    float wx[64];    // W_gates[gn, d = kh*64 + j],      j in [0,64)
    float wk[128];   // W_gates[gn, 128 + kh*128 + j],   j in [0,128)
    {
        const float4* p = reinterpret_cast<const float4*>(Wg + gn * 384 + kh * 64);
        #pragma unroll
        for (int j4 = 0; j4 < 16; ++j4) {
            float4 v = p[j4];
            wx[4*j4+0] = v.x; wx[4*j4+1] = v.y; wx[4*j4+2] = v.z; wx[4*j4+3] = v.w;
        }
        const float4* q = reinterpret_cast<const float4*>(Wg + gn * 384 + 128 + kh * 128);
        #pragma unroll
        for (int j4 = 0; j4 < 32; ++j4) {
            float4 v = q[j4];
            wk[4*j4+0] = v.x; wk[4*j4+1] = v.y; wk[4*j4+2] = v.z; wk[4*j4+3] = v.w;
        }
    }
    float wh[32];    // Wh[h = tid, n]
    {
        const float4* p = reinterpret_cast<const float4*>(Wh + tid * 32);
        #pragma unroll
        for (int j4 = 0; j4 < 8; ++j4) {
            float4 v = p[j4];
            wh[4*j4+0] = v.x; wh[4*j4+1] = v.y; wh[4*j4+2] = v.z; wh[4*j4+3] = v.w;
        }
    }
    const float bgv = bg[gn];
    const float bhv = bh[tid];

    float c = 0.0f;
    float hval = 0.0f;
    h_lds[tid] = 0.0f;
    __syncthreads();

    const float* xb   = x + (size_t)b * INDIM;
    float*       outb = out + (size_t)b * HIDDEN;

    for (int t = 0; t < T_STEPS; ++t) {
        // stage this step's x row into LDS (coalesced 512B)
        if (tid < INDIM)
            x_lds[tid] = xb[(size_t)t * (BATCH * INDIM) + tid];
        __syncthreads();
        // (this barrier also makes last step's h_lds writes visible)

        // ---- stage 1: z[gn] = comb . W_gates[gn,:]  (K=384, split 2 ways) ----
        float a0 = 0.f, a1 = 0.f, a2 = 0.f, a3 = 0.f;
        const float* xs = x_lds + kh * 64;
        #pragma unroll
        for (int j = 0; j < 64; j += 4) {
            float4 v = *reinterpret_cast<const float4*>(xs + j);   // wave-uniform broadcast
            a0 += v.x * wx[j];   a1 += v.y * wx[j+1];
            a2 += v.z * wx[j+2]; a3 += v.w * wx[j+3];
        }
        const float* hs = h_lds + kh * 128;
        #pragma unroll
        for (int j = 0; j < 128; j += 4) {
            float4 v = *reinterpret_cast<const float4*>(hs + j);   // wave-uniform broadcast
            a0 += v.x * wk[j];   a1 += v.y * wk[j+1];
            a2 += v.z * wk[j+2]; a3 += v.w * wk[j+3];
        }
        float s = (a0 + a1) + (a2 + a3);
        s += __shfl_xor(s, 1);          // combine the two k-halves (adjacent lanes)
        if (kh == 0) z_lds[gn] = s + bgv;
        __syncthreads();

        // ---- stage 2: h4[g, h=tid] = sum_n z[g*32+n]*wh[n] + bh ----
        float p0 = 0.f, p1 = 0.f, p2 = 0.f, p3 = 0.f;
        #pragma unroll
        for (int n = 0; n < 32; n += 4) {
            float4 z0 = *reinterpret_cast<const float4*>(z_lds + n);
            float4 z1 = *reinterpret_cast<const float4*>(z_lds + 32 + n);
            float4 z2 = *reinterpret_cast<const float4*>(z_lds + 64 + n);
            float4 z3 = *reinterpret_cast<const float4*>(z_lds + 96 + n);
            p0 += z0.x*wh[n] + z0.y*wh[n+1] + z0.z*wh[n+2] + z0.w*wh[n+3];
            p1 += z1.x*wh[n] + z1.y*wh[n+1] + z1.z*wh[n+2] + z1.w*wh[n+3];
            p2 += z2.x*wh[n] + z2.y*wh[n+1] + z2.z*wh[n+2] + z2.w*wh[n+3];
            p3 += z3.x*wh[n] + z3.y*wh[n+1] + z3.z*wh[n+2] + z3.w*wh[n+3];
        }
        float fg = sigmoid_f(p0 + bhv);
        float ig = sigmoid_f(p1 + bhv);
        float gg = tanh_f(p2 + bhv);
        float og = sigmoid_f(p3 + bhv);
        c    = fg * c + ig * gg;
        hval = og * tanh_f(c);

        h_lds[tid] = hval;   // consumed next iteration after the x-barrier
        outb[(size_t)t * (BATCH * HIDDEN) + tid] = hval;
        // NOTE: no barrier needed here; next iteration's x-barrier orders
        // h_lds writes (and z_lds reads) against next stage-1/stage-1's z write.
    }

    // final states: hx then cx
    const size_t off = (size_t)T_STEPS * BATCH * HIDDEN;
    out[off + (size_t)b * HIDDEN + tid]                         = hval;
    out[off + (size_t)BATCH * HIDDEN + (size_t)b * HIDDEN + tid] = c;
}

extern "C" void kernel_launch(void* const* d_in, const int* in_sizes, int n_in,
                              void* d_out, int out_size, void* d_ws, size_t ws_size,
                              hipStream_t stream) {
    const float* x  = (const float*)d_in[0];   // (512,256,128)
    const float* Wg = (const float*)d_in[1];   // (4,32,384)
    const float* bg = (const float*)d_in[2];   // (4,32)
    const float* Wh = (const float*)d_in[3];   // (256,32)
    const float* bh = (const float*)d_in[4];   // (256)
    float* out = (float*)d_out;

    qlstm_kernel<<<BATCH, 256, 0, stream>>>(x, Wg, bg, Wh, bh, out);
}

// Round 2
// 1294.392 us; speedup vs baseline: 1.0384x; 1.0384x over previous
//
#include <hip/hip_runtime.h>

// QLSTM recurrence, T=512, B=256, IN=128, HID=256, NQ=32, D=384.
// One block per batch row; 512 threads (8 waves = 2 waves/SIMD).
//
// Stage 1 (z = comb . Wg^T): thread t -> (gn = t&127, kq = t>>7).
//   kq is wave-uniform => LDS broadcast reads have ONE address per wave
//   (conflict-free). Per-thread weights: wq[96] = Wg[gn, kq*96 .. +96).
//   4 partials per gn combined with ds_add_f32 into gate-padded z buffer.
// Stage 2 (h4 = z . Wh^T): thread t -> (h = t>>1, gh = t&1); lane computes
//   gates {gh, gh+2}; pair-exchange via __shfl_xor(.,1); both lanes keep c.
// z double-buffered (parity t&1) so re-init never races prior-step readers.
// 2 barriers/step. x row prefetched one step ahead into a register.

#define T_STEPS 512
#define BATCH   256
#define INDIM   128
#define HIDDEN  256

__device__ __forceinline__ float sigmoid_f(float x) {
    return 1.0f / (1.0f + __expf(-x));
}
__device__ __forceinline__ float tanh_f(float x) {
    float e = __expf(2.0f * x);
    return (e - 1.0f) / (e + 1.0f);
}

// z buffer: 4 gates x 32, padded to 36 per gate so the 4 gate blocks start
// on distinct bank quads (gate g at float offset 36g).
#define ZPAD(i) ((i) + (((i) >> 5) << 2))

__global__ __launch_bounds__(512, 2) void qlstm_kernel(
    const float* __restrict__ x,    // (T,B,IN)
    const float* __restrict__ Wg,   // (4,32,384) row-major (row = gn)
    const float* __restrict__ bg,   // (4,32) flat = [gn]
    const float* __restrict__ Wh,   // (256,32)
    const float* __restrict__ bh,   // (256)
    float* __restrict__ out)        // T*B*HID ++ B*HID ++ B*HID
{
    __shared__ float comb[INDIM + HIDDEN];   // [x(128) | h(256)]
    __shared__ float zbuf[2][144];           // gate-padded, double-buffered

    const int tid = threadIdx.x;
    const int b   = blockIdx.x;
    const int gn  = tid & 127;   // stage-1 column
    const int kq  = tid >> 7;    // stage-1 K-quarter (wave-uniform)
    const int h   = tid >> 1;    // stage-2 hidden unit
    const int gh  = tid & 1;     // stage-2 gate parity

    // ---- one-time weight loads (per-thread registers) ----
    float wq[96];   // Wg[gn, kq*96 .. kq*96+96)
    {
        const float4* p = reinterpret_cast<const float4*>(Wg + gn * 384 + kq * 96);
        #pragma unroll
        for (int j4 = 0; j4 < 24; ++j4) {
            float4 v = p[j4];
            wq[4*j4+0] = v.x; wq[4*j4+1] = v.y; wq[4*j4+2] = v.z; wq[4*j4+3] = v.w;
        }
    }
    float wh[32];   // Wh[h, :]
    {
        const float4* p = reinterpret_cast<const float4*>(Wh + h * 32);
        #pragma unroll
        for (int j4 = 0; j4 < 8; ++j4) {
            float4 v = p[j4];
            wh[4*j4+0] = v.x; wh[4*j4+1] = v.y; wh[4*j4+2] = v.z; wh[4*j4+3] = v.w;
        }
    }
    const float bg0 = (tid < 128) ? bg[tid] : 0.0f;
    const float bhv = bh[h];

    float c = 0.0f, hval = 0.0f;
    if (tid < HIDDEN) comb[INDIM + tid] = 0.0f;   // h0 = 0

    const float* xb   = x + (size_t)b * INDIM;
    float*       outb = out + (size_t)b * HIDDEN;

    // prefetch x row for t=0
    float xreg = (tid < INDIM) ? xb[tid] : 0.0f;

    for (int t = 0; t < T_STEPS; ++t) {
        const int q = t & 1;

        // ---- phase 1: stage x row, (re)init z buffer with bias ----
        if (tid < INDIM) comb[tid] = xreg;
        if (tid < 128)   zbuf[q][ZPAD(tid)] = bg0;
        __syncthreads();

        // prefetch next step's x (latency hides under stage 1/2)
        if (tid < INDIM) {
            int tn = (t + 1 < T_STEPS) ? (t + 1) : t;
            xreg = xb[(size_t)tn * (BATCH * INDIM) + tid];
        }

        // ---- stage 1: partial dot over this thread's K-quarter ----
        float a0 = 0.f, a1 = 0.f, a2 = 0.f, a3 = 0.f;
        const float* cs = comb + kq * 96;   // wave-uniform base
        #pragma unroll
        for (int j = 0; j < 96; j += 4) {
            float4 v = *reinterpret_cast<const float4*>(cs + j);  // 1 addr/wave
            a0 += v.x * wq[j];   a1 += v.y * wq[j+1];
            a2 += v.z * wq[j+2]; a3 += v.w * wq[j+3];
        }
        atomicAdd(&zbuf[q][ZPAD(gn)], (a0 + a1) + (a2 + a3));    // ds_add_f32
        __syncthreads();

        // ---- stage 2: two K=32 dots (gates gh and gh+2) ----
        const float* za = zbuf[q] + 36 * gh;        // even: gate0, odd: gate1
        const float* zb = zbuf[q] + 36 * (gh + 2);  // even: gate2, odd: gate3
        float pa0 = 0.f, pa1 = 0.f, pb0 = 0.f, pb1 = 0.f;
        #pragma unroll
        for (int n = 0; n < 32; n += 4) {
            float4 va = *reinterpret_cast<const float4*>(za + n);
            float4 vb = *reinterpret_cast<const float4*>(zb + n);
            pa0 += va.x * wh[n]   + va.y * wh[n+1];
            pa1 += va.z * wh[n+2] + va.w * wh[n+3];
            pb0 += vb.x * wh[n]   + vb.y * wh[n+1];
            pb1 += vb.z * wh[n+2] + vb.w * wh[n+3];
        }
        float pA = pa0 + pa1;   // even: f-pre, odd: i-pre
        float pB = pb0 + pb1;   // even: g-pre, odd: o-pre
        float oA = __shfl_xor(pA, 1);
        float oB = __shfl_xor(pB, 1);
        float pf = gh ? oA : pA;
        float pi = gh ? pA : oA;
        float pg = gh ? oB : pB;
        float po = gh ? pB : oB;

        float fg = sigmoid_f(pf + bhv);
        float ig = sigmoid_f(pi + bhv);
        float gg = tanh_f(pg + bhv);
        float og = sigmoid_f(po + bhv);
        c    = fg * c + ig * gg;          // both lanes keep identical c
        hval = og * tanh_f(c);

        if (!gh) {
            comb[INDIM + h] = hval;       // consumed next step after barrier
            outb[(size_t)t * (BATCH * HIDDEN) + h] = hval;
        }
        // no barrier here: phase-1 of t+1 touches only x region + other z buf;
        // next __syncthreads orders comb/h and z reads.
    }

    if (!gh) {
        const size_t off = (size_t)T_STEPS * BATCH * HIDDEN;
        out[off + (size_t)b * HIDDEN + h]                          = hval;
        out[off + (size_t)BATCH * HIDDEN + (size_t)b * HIDDEN + h] = c;
    }
}

extern "C" void kernel_launch(void* const* d_in, const int* in_sizes, int n_in,
                              void* d_out, int out_size, void* d_ws, size_t ws_size,
                              hipStream_t stream) {
    const float* x  = (const float*)d_in[0];   // (512,256,128)
    const float* Wg = (const float*)d_in[1];   // (4,32,384)
    const float* bg = (const float*)d_in[2];   // (4,32)
    const float* Wh = (const float*)d_in[3];   // (256,32)
    const float* bh = (const float*)d_in[4];   // (256)
    float* out = (float*)d_out;

    qlstm_kernel<<<BATCH, 512, 0, stream>>>(x, Wg, bg, Wh, bh, out);
}

// Round 3
// 1188.393 us; speedup vs baseline: 1.1310x; 1.0892x over previous
//
#include <hip/hip_runtime.h>

// QLSTM recurrence, T=512, B=256, IN=128, HID=256, NQ=32, D=384.
// One block per batch row; 512 threads (8 waves = 2 waves/SIMD, 1 block/CU).
//
// Weight placement (the round-1/2 lesson: compiler refuses to keep >64-float
// arrays in VGPRs and re-loads from global every step, exposing L2 latency):
//   - Wg_h (128 gn x 256 k, 131 KB) -> LDS, layout [k/4][gn][4] so stage-1
//     reads are ds_read_b128 with consecutive lanes = conflict-free.
//   - Wg_x slice (32 f) + Wh row (32 f) -> per-thread registers (small).
// Stage 1: thread (gn = tid&127, kq = tid>>7); kq wave-uniform so h/x reads
//   are LDS broadcasts. Partials combined with ds_add_f32 into padded zbuf.
// Stage 2: thread (h = tid>>1, gh = tid&1): gates {gh, gh+2}, pair-exchange
//   via shfl_xor(1); both lanes replicate c.
// 2 barriers/step; z double-buffered; x prefetched one step ahead.

#define T_STEPS 512
#define BATCH   256
#define INDIM   128
#define HIDDEN  256

// dynamic LDS layout (in floats):
//   [0, 32768)         wgh[k4][gn][e] : Wg_h[gn][4*k4+e]   (64 x 128 x 4)
//   [32768, 33152)     comb[384] : x = 0..127, h = 128..383
//   [33152, 33440)     zbuf[2][144]  (4 gates x 32, padded to 36/gate)
#define WGH_OFF   0
#define COMB_OFF  32768
#define ZBUF_OFF  33152
#define LDS_FLOATS (ZBUF_OFF + 2*144)
#define LDS_BYTES  (LDS_FLOATS * 4)

#define ZPAD(i) ((i) + (((i) >> 5) << 2))

__device__ __forceinline__ float sigmoid_f(float x) {
    return 1.0f / (1.0f + __expf(-x));
}
__device__ __forceinline__ float tanh_f(float x) {
    float e = __expf(2.0f * x);
    return (e - 1.0f) / (e + 1.0f);
}

__global__ __launch_bounds__(512, 2) void qlstm_kernel(
    const float* __restrict__ x,    // (T,B,IN)
    const float* __restrict__ Wg,   // (4,32,384) row-major (row = gn)
    const float* __restrict__ bg,   // (4,32) flat [gn]
    const float* __restrict__ Wh,   // (256,32)
    const float* __restrict__ bh,   // (256)
    float* __restrict__ out)        // T*B*HID ++ B*HID ++ B*HID
{
    extern __shared__ float lds[];
    float* wgh  = lds + WGH_OFF;
    float* comb = lds + COMB_OFF;   // [x(128) | h(256)]
    float* zbuf = lds + ZBUF_OFF;   // [2][144]

    const int tid = threadIdx.x;
    const int b   = blockIdx.x;
    const int gn  = tid & 127;   // stage-1 column
    const int kq  = tid >> 7;    // stage-1 K-quarter (wave-uniform)
    const int h2  = tid >> 1;    // stage-2 hidden unit
    const int gh  = tid & 1;     // stage-2 gate parity

    // ---- one-time: stage Wg_h into LDS, transposed-quad layout ----
    // element e = (gn<<8)|k ; global = Wg[gn*384 + 128 + k] (coalesced reads)
    #pragma unroll
    for (int i = 0; i < 64; ++i) {
        int e = i * 512 + tid;
        int g = e >> 8;          // gn
        int k = e & 255;
        wgh[(k >> 2) * 512 + g * 4 + (k & 3)] = Wg[g * 384 + 128 + k];
    }

    // ---- one-time: small per-thread register weights ----
    float wx[32];   // Wg_x[gn, kq*32 .. +32)
    {
        const float4* p = reinterpret_cast<const float4*>(Wg + gn * 384 + kq * 32);
        #pragma unroll
        for (int j4 = 0; j4 < 8; ++j4) {
            float4 v = p[j4];
            wx[4*j4+0] = v.x; wx[4*j4+1] = v.y; wx[4*j4+2] = v.z; wx[4*j4+3] = v.w;
        }
    }
    float wh[32];   // Wh[h2, :]
    {
        const float4* p = reinterpret_cast<const float4*>(Wh + h2 * 32);
        #pragma unroll
        for (int j4 = 0; j4 < 8; ++j4) {
            float4 v = p[j4];
            wh[4*j4+0] = v.x; wh[4*j4+1] = v.y; wh[4*j4+2] = v.z; wh[4*j4+3] = v.w;
        }
    }
    const float bg0 = (tid < 128) ? bg[tid] : 0.0f;
    const float bhv = bh[h2];

    float c = 0.0f, hval = 0.0f;
    if (tid < HIDDEN) comb[INDIM + tid] = 0.0f;   // h0 = 0

    const float* xb   = x + (size_t)b * INDIM;
    float*       outb = out + (size_t)b * HIDDEN;

    float xreg = (tid < INDIM) ? xb[tid] : 0.0f;   // prefetch t=0

    for (int t = 0; t < T_STEPS; ++t) {
        float* zq = zbuf + (t & 1) * 144;

        // phase A: stage x row, init z with bias (barrier orders wgh fill,
        // previous-step h writes, and this-step z-init before stage 1)
        if (tid < INDIM) comb[tid] = xreg;
        if (tid < 128)   zq[ZPAD(tid)] = bg0;
        __syncthreads();

        // prefetch next x row (hides under stages 1+2)
        if (tid < INDIM) {
            int tn = (t + 1 < T_STEPS) ? (t + 1) : t;
            xreg = xb[(size_t)tn * (BATCH * INDIM) + tid];
        }

        // ---- stage 1: z[gn] partial over this thread's K-quarter ----
        float a0 = 0.f, a1 = 0.f, a2 = 0.f, a3 = 0.f;
        const float4* wrow = reinterpret_cast<const float4*>(wgh) + kq * 16 * 128 + gn;
        const float4* hrow = reinterpret_cast<const float4*>(comb + INDIM + kq * 64);
        #pragma unroll
        for (int j4 = 0; j4 < 16; ++j4) {
            float4 w  = wrow[(size_t)j4 * 128];   // conflict-free b128
            float4 hv = hrow[j4];                 // wave-uniform broadcast
            a0 += w.x * hv.x; a1 += w.y * hv.y;
            a2 += w.z * hv.z; a3 += w.w * hv.w;
        }
        const float4* xrow = reinterpret_cast<const float4*>(comb + kq * 32);
        #pragma unroll
        for (int j4 = 0; j4 < 8; ++j4) {
            float4 xv = xrow[j4];                 // wave-uniform broadcast
            a0 += xv.x * wx[4*j4+0]; a1 += xv.y * wx[4*j4+1];
            a2 += xv.z * wx[4*j4+2]; a3 += xv.w * wx[4*j4+3];
        }
        atomicAdd(&zq[ZPAD(gn)], (a0 + a1) + (a2 + a3));   // ds_add_f32
        __syncthreads();

        // ---- stage 2: gates {gh, gh+2} for hidden unit h2 ----
        const float* za = zq + 36 * gh;
        const float* zc = zq + 36 * (gh + 2);
        float pa0 = 0.f, pa1 = 0.f, pb0 = 0.f, pb1 = 0.f;
        #pragma unroll
        for (int n = 0; n < 32; n += 4) {
            float4 va = *reinterpret_cast<const float4*>(za + n);  // 2 addrs/wave
            float4 vb = *reinterpret_cast<const float4*>(zc + n);
            pa0 += va.x * wh[n]   + va.y * wh[n+1];
            pa1 += va.z * wh[n+2] + va.w * wh[n+3];
            pb0 += vb.x * wh[n]   + vb.y * wh[n+1];
            pb1 += vb.z * wh[n+2] + vb.w * wh[n+3];
        }
        float pA = pa0 + pa1;   // even: f-pre, odd: i-pre
        float pB = pb0 + pb1;   // even: g-pre, odd: o-pre
        float oA = __shfl_xor(pA, 1);
        float oB = __shfl_xor(pB, 1);
        float pf = gh ? oA : pA;
        float pi = gh ? pA : oA;
        float pg = gh ? oB : pB;
        float po = gh ? pB : oB;

        float fg = sigmoid_f(pf + bhv);
        float ig = sigmoid_f(pi + bhv);
        float gg = tanh_f(pg + bhv);
        float og = sigmoid_f(po + bhv);
        c    = fg * c + ig * gg;          // both lanes replicate c
        hval = og * tanh_f(c);

        if (!gh) {
            comb[INDIM + h2] = hval;      // read next step after barrier A
            outb[(size_t)t * (BATCH * HIDDEN) + h2] = hval;
        }
        // no barrier here: next iter writes only x region + other z buffer,
        // both ordered by barrier A before anyone reads them.
    }

    if (!gh) {
        const size_t off = (size_t)T_STEPS * BATCH * HIDDEN;
        out[off + (size_t)b * HIDDEN + h2]                          = hval;
        out[off + (size_t)BATCH * HIDDEN + (size_t)b * HIDDEN + h2] = c;
    }
}

extern "C" void kernel_launch(void* const* d_in, const int* in_sizes, int n_in,
                              void* d_out, int out_size, void* d_ws, size_t ws_size,
                              hipStream_t stream) {
    const float* x  = (const float*)d_in[0];   // (512,256,128)
    const float* Wg = (const float*)d_in[1];   // (4,32,384)
    const float* bg = (const float*)d_in[2];   // (4,32)
    const float* Wh = (const float*)d_in[3];   // (256,32)
    const float* bh = (const float*)d_in[4];   // (256)
    float* out = (float*)d_out;

    static int lds_set = 0;
    (void)lds_set;  // hipFuncSetAttribute is host-side & idempotent; safe under capture
    hipFuncSetAttribute((const void*)qlstm_kernel,
                        hipFuncAttributeMaxDynamicSharedMemorySize, LDS_BYTES);

    qlstm_kernel<<<BATCH, 512, LDS_BYTES, stream>>>(x, Wg, bg, Wh, bh, out);
}